// Round 5
// baseline (271.871 us; speedup 1.0000x reference)
//
#include <hip/hip_runtime.h>
#include <cstddef>

// Problem shapes (fixed by reference)
#define NBH  1024   // B*H
#define Mm   196
#define Dd   128
#define MIDe 64
#define DVv  128
#define WQLD 136    // WqT row length in shorts (128 + 8 pad -> 272 B rows,
                    // rotates banks by 4/row -> frag reads conflict-free)

typedef __attribute__((ext_vector_type(8))) short bf16x8;  // 8 bf16 in 4 VGPRs
typedef __attribute__((ext_vector_type(4))) float f32x4;   // MFMA C/D frag

__device__ __forceinline__ short f2bf(float x) {           // fp32 -> bf16 RNE
    union { float f; unsigned u; } v; v.f = x;
    return (short)((v.u + 0x7FFFu + ((v.u >> 16) & 1u)) >> 16);
}

__device__ __forceinline__ float waveReduceSum(float v) {
#pragma unroll
    for (int off = 32; off > 0; off >>= 1) v += __shfl_xor(v, off, 64);
    return v;
}

// Single-pass fused kernel: per m-tile, compute h-row logits via MFMA and
// IMMEDIATELY accumulate value2 with online (flash-style) softmax per wave.
//
// Register discipline (rounds 3/4 spilled ~52 MB of scratch): the spill
// source was 16 DATA-DEPENDENT value2 row addresses (min-clamp per row ->
// 16 live 64-bit address pairs ~32 VGPRs). Fixed by immediate-offset
// addressing: two per-lane bases + compile-time offsets (i*512B < 4096),
// wave-uniform tail branch for mt==12 (4 valid rows, rest zero -- their
// p is exactly 0 so zeros are mathematically inert).
__global__ __launch_bounds__(256, 4)
void scatt_fused(const float* __restrict__ query,
                 const float* __restrict__ key,
                 const float* __restrict__ att_mask,
                 const float* __restrict__ value1,
                 const float* __restrict__ value2,
                 const float* __restrict__ W_basic,
                 const float* __restrict__ b_basic,
                 const float* __restrict__ W_spatial,
                 const float* __restrict__ b_spatial,
                 const float* __restrict__ W_channel,
                 const float* __restrict__ b_channel,
                 float* __restrict__ out)
{
    __shared__ short wqT[MIDe][WQLD];   // bf16 Wq^T[e][d], built once per block
    __shared__ float qS[Dd];
    __shared__ float maskS[Mm];
    __shared__ float poolPart[4][MIDe];
    __shared__ float poolS[MIDe];
    __shared__ float accW[4][DVv];      // per-wave online v2 numerator
    __shared__ float mW[4], lW[4], cntW[4];

    const int t    = threadIdx.x;
    const int lane = t & 63;
    const int w    = t >> 6;            // wave id 0..3
    const int ln15 = lane & 15;
    const int q4   = lane >> 4;         // quad id 0..3
    const int bh   = blockIdx.x;
    const int b    = bh >> 3;

    const float* __restrict__ keyB  = key      + (size_t)bh * Mm * Dd;
    const float* __restrict__ val2B = value2   + (size_t)bh * Mm * DVv;
    const float* __restrict__ qB    = query    + (size_t)bh * Dd;
    const float* __restrict__ maskB = att_mask + (size_t)b  * Mm;

    // ---- Phase 0a: stage q + mask ----
    if (t < 32) ((float4*)qS)[t] = ((const float4*)qB)[t];
    for (int i = t; i < Mm; i += 256) maskS[i] = maskB[i];
    __syncthreads();

    // ---- Phase 0b: build WqT[e][d] = bf16(q[d]*W_basic[d][e]) cooperatively.
    {
        const int e0 = lane;            // e column this thread fills
        const int d0 = w * 32;
#pragma unroll
        for (int c = 0; c < 4; ++c) {   // 4 chunks of 8 d-values
            short pk[8];
#pragma unroll
            for (int j = 0; j < 8; ++j) {
                const int d = d0 + c * 8 + j;
                pk[j] = f2bf(qS[d] * W_basic[d * MIDe + e0]);
            }
            *(bf16x8*)&wqT[e0][d0 + c * 8] = *(bf16x8*)pk;  // ds_write_b128
        }
    }
    __syncthreads();

    float bbv[4], wspv[4];
#pragma unroll
    for (int nt = 0; nt < 4; ++nt) {
        bbv[nt]  = b_basic[nt * 16 + ln15];
        wspv[nt] = W_spatial[nt * 16 + ln15];
    }
    const float bsp = b_spatial[0];

    float poolAcc[4] = {0.f, 0.f, 0.f, 0.f};
    // per-wave online-softmax state; this lane owns v2 cols {2*lane, 2*lane+1}
    float m_run = -3.0e38f;
    float l_run = 0.f;
    float2 av   = make_float2(0.f, 0.f);

    // ---- Main loop: 13 m-tiles of 16, wave w owns {w, w+4, w+8, w+12<13} ----
    for (int mt = w; mt < 13; mt += 4) {
        // A-tile loads (key): one address pair + folded immediate offsets
        const int mrow = min(mt * 16 + ln15, Mm - 1);
        const float* ap = keyB + (size_t)mrow * Dd + q4 * 8;
        float4 a0[4], a1[4];
#pragma unroll
        for (int ks = 0; ks < 4; ++ks) {
            a0[ks] = *(const float4*)(ap + ks * 32);
            a1[ks] = *(const float4*)(ap + ks * 32 + 4);
        }

        // value2: two per-lane bases, compile-time row offsets (i*512B<4096).
        // Wave-uniform tail branch: mt==12 has 4 valid rows (192..195); the
        // rest get vv=0 (their logit is -1e9/-3e38 -> p==0 -> inert).
        const float* vp0 = val2B + (size_t)(mt * 16) * DVv + 2 * lane;
        const float* vp1 = vp0 + 8 * DVv;
        float2 vv0[8], vv1[8];
        if (mt < 12) {
            // first half issued before the key-load wait -> in flight
            // during the MFMA chain
#pragma unroll
            for (int i = 0; i < 8; ++i)
                vv0[i] = *(const float2*)(vp0 + i * DVv);
        } else {
#pragma unroll
            for (int i = 0; i < 4; ++i)
                vv0[i] = *(const float2*)(vp0 + i * DVv);
#pragma unroll
            for (int i = 4; i < 8; ++i) vv0[i] = make_float2(0.f, 0.f);
#pragma unroll
            for (int i = 0; i < 8; ++i) vv1[i] = make_float2(0.f, 0.f);
        }

        // Convert key tile to bf16 fragments NOW (waits key loads only,
        // vv0 stays outstanding); frees a0/a1 before the MFMA chain.
        bf16x8 af[4];
#pragma unroll
        for (int ks = 0; ks < 4; ++ks) {
            af[ks] = bf16x8{ f2bf(a0[ks].x), f2bf(a0[ks].y),
                             f2bf(a0[ks].z), f2bf(a0[ks].w),
                             f2bf(a1[ks].x), f2bf(a1[ks].y),
                             f2bf(a1[ks].z), f2bf(a1[ks].w) };
        }

        f32x4 acc[4] = {f32x4{0,0,0,0}, f32x4{0,0,0,0},
                        f32x4{0,0,0,0}, f32x4{0,0,0,0}};
#pragma unroll
        for (int ks = 0; ks < 4; ++ks) {
#pragma unroll
            for (int nt = 0; nt < 4; ++nt) {
                // re-read B-frag from LDS per tile (conflict-free ds_read_b128)
                const bf16x8 bk =
                    *(const bf16x8*)&wqT[nt * 16 + ln15][ks * 32 + q4 * 8];
                acc[nt] = __builtin_amdgcn_mfma_f32_16x16x32_bf16(
                              af[ks], bk, acc[nt], 0, 0, 0);
            }
        }

        // value2 second half: latency hides under the epilogue shuffles.
        if (mt < 12) {
#pragma unroll
            for (int i = 0; i < 8; ++i)
                vv1[i] = *(const float2*)(vp1 + i * DVv);
        }

        // Epilogue: C/D layout col = ln15 (e), row = q4*4 + r (m within tile)
        float sR[4];
#pragma unroll
        for (int r = 0; r < 4; ++r) {
            const int m = mt * 16 + q4 * 4 + r;
            const bool valid = m < Mm;
            const float msk = valid ? maskS[m] : 0.f;
            float srow = 0.f;
#pragma unroll
            for (int nt = 0; nt < 4; ++nt) {
                float hv = acc[nt][r] + bbv[nt];
                hv = hv > 0.f ? hv : 0.f;                 // relu
                poolAcc[nt] = fmaf(hv, msk, poolAcc[nt]); // masked pool partial
                srow = fmaf(hv, wspv[nt], srow);          // h[m,:].W_spatial
            }
            srow += __shfl_xor(srow, 1, 64);
            srow += __shfl_xor(srow, 2, 64);
            srow += __shfl_xor(srow, 4, 64);
            srow += __shfl_xor(srow, 8, 64);
            // masked logit: -1e9 (matches reference); invalid rows -> -3e38
            sR[r] = valid ? (msk == 0.f ? -1.0e9f : srow + bsp) : -3.0e38f;
        }

        // broadcast all 16 row-logits of the tile to every lane
        // row i (= q4'*4 + r') lives in lanes q4'=i>>2, register sR[i&3]
        float sv[16];
#pragma unroll
        for (int i = 0; i < 16; ++i)
            sv[i] = __shfl(sR[i & 3], (i >> 2) << 4, 64);

        float tm = sv[0];
#pragma unroll
        for (int i = 1; i < 16; ++i) tm = fmaxf(tm, sv[i]);

        // online-softmax update (per wave). Masked rows at -1e9 are killed
        // at the cross-wave merge by exp(mW - M_global).
        const float newm = fmaxf(m_run, tm);
        const float sc = __expf(m_run - newm);
        m_run = newm;
        l_run *= sc;
        av.x *= sc; av.y *= sc;
#pragma unroll
        for (int i = 0; i < 8; ++i) {
            const float p = __expf(sv[i] - newm);   // 0 for invalid/masked
            l_run += p;
            av.x = fmaf(p, vv0[i].x, av.x);
            av.y = fmaf(p, vv0[i].y, av.y);
        }
#pragma unroll
        for (int i = 0; i < 8; ++i) {
            const float p = __expf(sv[8 + i] - newm);
            l_run += p;
            av.x = fmaf(p, vv1[i].x, av.x);
            av.y = fmaf(p, vv1[i].y, av.y);
        }
    }

    // ---- pool: reduce the 4 row-quads (same e, different m) across q4 ----
#pragma unroll
    for (int nt = 0; nt < 4; ++nt) {
        poolAcc[nt] += __shfl_xor(poolAcc[nt], 16, 64);
        poolAcc[nt] += __shfl_xor(poolAcc[nt], 32, 64);
    }
    if (lane < 16) {
#pragma unroll
        for (int nt = 0; nt < 4; ++nt)
            poolPart[w][nt * 16 + lane] = poolAcc[nt];
    }
    // mask count partial (wave w covers rows [64w, 64w+64))
    {
        const int mi = w * 64 + lane;
        float cm = (mi < Mm) ? maskS[mi] : 0.f;
        cm = waveReduceSum(cm);
        if (lane == 0) cntW[w] = cm;
    }
    // publish per-wave online state
    if (lane == 0) { mW[w] = m_run; lW[w] = l_run; }
    ((float2*)&accW[w][0])[lane] = av;
    __syncthreads();

    // ---- merge 4 waves' online states; finalize pool ----
    float v2v = 0.f;
    if (t < DVv) {
        const float M = fmaxf(fmaxf(mW[0], mW[1]), fmaxf(mW[2], mW[3]));
        float L = 0.f;
#pragma unroll
        for (int i = 0; i < 4; ++i) {
            const float s = __expf(mW[i] - M);
            L   = fmaf(lW[i], s, L);
            v2v = fmaf(accW[i][t], s, v2v);
        }
        v2v /= L;
    }
    if (t < MIDe) {
        const float cnt = cntW[0] + cntW[1] + cntW[2] + cntW[3];
        poolS[t] = (poolPart[0][t] + poolPart[1][t] +
                    poolPart[2][t] + poolPart[3][t]) / cnt;
    }
    __syncthreads();

    // ---- channel gate + epilogue: out = value1 * v2 * sigmoid(pool@Wc+b) ----
    if (t < DVv) {
        float a = b_channel[t];
#pragma unroll 8
        for (int e = 0; e < MIDe; ++e)
            a = fmaf(poolS[e], W_channel[e * DVv + t], a);  // coalesced over t
        const float chv = 1.f / (1.f + __expf(-a));
        out[(size_t)bh * DVv + t] = value1[(size_t)bh * DVv + t] * v2v * chv;
    }
}

extern "C" void kernel_launch(void* const* d_in, const int* in_sizes, int n_in,
                              void* d_out, int out_size, void* d_ws, size_t ws_size,
                              hipStream_t stream) {
    const float* query     = (const float*)d_in[0];
    const float* key       = (const float*)d_in[1];
    const float* att_mask  = (const float*)d_in[2];
    const float* value1    = (const float*)d_in[3];
    const float* value2    = (const float*)d_in[4];
    const float* W_basic   = (const float*)d_in[5];
    const float* b_basic   = (const float*)d_in[6];
    const float* W_spatial = (const float*)d_in[7];
    const float* b_spatial = (const float*)d_in[8];
    const float* W_channel = (const float*)d_in[9];
    const float* b_channel = (const float*)d_in[10];
    float* out = (float*)d_out;

    scatt_fused<<<NBH, 256, 0, stream>>>(query, key, att_mask, value1, value2,
                                         W_basic, b_basic, W_spatial, b_spatial,
                                         W_channel, b_channel, out);
}

// Round 6
// 246.779 us; speedup vs baseline: 1.1017x; 1.1017x over previous
//
#include <hip/hip_runtime.h>
#include <cstddef>

// Problem shapes (fixed by reference)
#define NBH  1024   // B*H
#define Mm   196
#define Dd   128
#define MIDe 64
#define DVv  128
#define WQLD 136    // WqT row length in shorts (128 + 8 pad -> 272 B rows,
                    // rotates banks by 4/row -> frag reads conflict-free)

typedef __attribute__((ext_vector_type(8))) short bf16x8;  // 8 bf16 in 4 VGPRs
typedef __attribute__((ext_vector_type(4))) float f32x4;   // MFMA C/D frag

__device__ __forceinline__ short f2bf(float x) {           // fp32 -> bf16 RNE
    union { float f; unsigned u; } v; v.f = x;
    return (short)((v.u + 0x7FFFu + ((v.u >> 16) & 1u)) >> 16);
}

__device__ __forceinline__ float waveReduceSum(float v) {
#pragma unroll
    for (int off = 32; off > 0; off >>= 1) v += __shfl_xor(v, off, 64);
    return v;
}

// Single-pass fused kernel: per m-tile, compute h-row logits via MFMA and
// IMMEDIATELY accumulate value2 with online (flash-style) softmax per wave.
//
// Register-budget model (rounds 3-5 all spilled ~52-62 MB of scratch):
// launch_bounds(256, 4) caps TOTAL regs (arch+AGPR, unified file) at 128.
// The barrier-free main loop lets the scheduler pipeline next-iteration
// loads into the current epilogue -> live demand ~220 regs -> ~90 spilled.
// Baseline (two-phase) demand was ~128: fit exactly, no spill -- consistent.
// FIX: launch_bounds(256, 2) -> 256-reg budget. Demand fits, spills gone,
// cross-iteration load pipelining (the latency hiding we want) preserved.
// Occupancy 2 waves/SIMD = 8 waves/CU: ~128 KB of loads in flight per CU,
// far above the ~22 KB needed to sustain ~6 TB/s at ~900 cyc HBM latency.
__global__ __launch_bounds__(256, 2)
void scatt_fused(const float* __restrict__ query,
                 const float* __restrict__ key,
                 const float* __restrict__ att_mask,
                 const float* __restrict__ value1,
                 const float* __restrict__ value2,
                 const float* __restrict__ W_basic,
                 const float* __restrict__ b_basic,
                 const float* __restrict__ W_spatial,
                 const float* __restrict__ b_spatial,
                 const float* __restrict__ W_channel,
                 const float* __restrict__ b_channel,
                 float* __restrict__ out)
{
    __shared__ short wqT[MIDe][WQLD];   // bf16 Wq^T[e][d], built once per block
    __shared__ float qS[Dd];
    __shared__ float maskS[Mm];
    __shared__ float poolPart[4][MIDe];
    __shared__ float poolS[MIDe];
    __shared__ float accW[4][DVv];      // per-wave online v2 numerator
    __shared__ float mW[4], lW[4], cntW[4];

    const int t    = threadIdx.x;
    const int lane = t & 63;
    const int w    = t >> 6;            // wave id 0..3
    const int ln15 = lane & 15;
    const int q4   = lane >> 4;         // quad id 0..3
    const int bh   = blockIdx.x;
    const int b    = bh >> 3;

    const float* __restrict__ keyB  = key      + (size_t)bh * Mm * Dd;
    const float* __restrict__ val2B = value2   + (size_t)bh * Mm * DVv;
    const float* __restrict__ qB    = query    + (size_t)bh * Dd;
    const float* __restrict__ maskB = att_mask + (size_t)b  * Mm;

    // ---- Phase 0a: stage q + mask ----
    if (t < 32) ((float4*)qS)[t] = ((const float4*)qB)[t];
    for (int i = t; i < Mm; i += 256) maskS[i] = maskB[i];
    __syncthreads();

    // ---- Phase 0b: build WqT[e][d] = bf16(q[d]*W_basic[d][e]) cooperatively.
    {
        const int e0 = lane;            // e column this thread fills
        const int d0 = w * 32;
#pragma unroll
        for (int c = 0; c < 4; ++c) {   // 4 chunks of 8 d-values
            short pk[8];
#pragma unroll
            for (int j = 0; j < 8; ++j) {
                const int d = d0 + c * 8 + j;
                pk[j] = f2bf(qS[d] * W_basic[d * MIDe + e0]);
            }
            *(bf16x8*)&wqT[e0][d0 + c * 8] = *(bf16x8*)pk;  // ds_write_b128
        }
    }
    __syncthreads();

    float bbv[4], wspv[4];
#pragma unroll
    for (int nt = 0; nt < 4; ++nt) {
        bbv[nt]  = b_basic[nt * 16 + ln15];
        wspv[nt] = W_spatial[nt * 16 + ln15];
    }
    const float bsp = b_spatial[0];

    float poolAcc[4] = {0.f, 0.f, 0.f, 0.f};
    // per-wave online-softmax state; this lane owns v2 cols {2*lane, 2*lane+1}
    float m_run = -3.0e38f;
    float l_run = 0.f;
    float2 av   = make_float2(0.f, 0.f);

    // ---- Main loop: 13 m-tiles of 16, wave w owns {w, w+4, w+8, w+12<13} ----
    for (int mt = w; mt < 13; mt += 4) {
        // A-tile loads (key): one address pair + folded immediate offsets
        const int mrow = min(mt * 16 + ln15, Mm - 1);
        const float* ap = keyB + (size_t)mrow * Dd + q4 * 8;
        float4 a0[4], a1[4];
#pragma unroll
        for (int ks = 0; ks < 4; ++ks) {
            a0[ks] = *(const float4*)(ap + ks * 32);
            a1[ks] = *(const float4*)(ap + ks * 32 + 4);
        }

        // value2: two per-lane bases, compile-time row offsets (i*512B<4096).
        // Wave-uniform tail branch: mt==12 has 4 valid rows (192..195); the
        // rest get vv=0 (their logit is -1e9/-3e38 -> p==0 -> inert).
        const float* vp0 = val2B + (size_t)(mt * 16) * DVv + 2 * lane;
        const float* vp1 = vp0 + 8 * DVv;
        float2 vv0[8], vv1[8];
        if (mt < 12) {
            // first half issued before the key-load wait -> in flight
            // during the MFMA chain
#pragma unroll
            for (int i = 0; i < 8; ++i)
                vv0[i] = *(const float2*)(vp0 + i * DVv);
        } else {
#pragma unroll
            for (int i = 0; i < 4; ++i)
                vv0[i] = *(const float2*)(vp0 + i * DVv);
#pragma unroll
            for (int i = 4; i < 8; ++i) vv0[i] = make_float2(0.f, 0.f);
#pragma unroll
            for (int i = 0; i < 8; ++i) vv1[i] = make_float2(0.f, 0.f);
        }

        // Convert key tile to bf16 fragments NOW (waits key loads only,
        // vv0 stays outstanding); frees a0/a1 before the MFMA chain.
        bf16x8 af[4];
#pragma unroll
        for (int ks = 0; ks < 4; ++ks) {
            af[ks] = bf16x8{ f2bf(a0[ks].x), f2bf(a0[ks].y),
                             f2bf(a0[ks].z), f2bf(a0[ks].w),
                             f2bf(a1[ks].x), f2bf(a1[ks].y),
                             f2bf(a1[ks].z), f2bf(a1[ks].w) };
        }

        f32x4 acc[4] = {f32x4{0,0,0,0}, f32x4{0,0,0,0},
                        f32x4{0,0,0,0}, f32x4{0,0,0,0}};
#pragma unroll
        for (int ks = 0; ks < 4; ++ks) {
#pragma unroll
            for (int nt = 0; nt < 4; ++nt) {
                // re-read B-frag from LDS per tile (conflict-free ds_read_b128)
                const bf16x8 bk =
                    *(const bf16x8*)&wqT[nt * 16 + ln15][ks * 32 + q4 * 8];
                acc[nt] = __builtin_amdgcn_mfma_f32_16x16x32_bf16(
                              af[ks], bk, acc[nt], 0, 0, 0);
            }
        }

        // value2 second half: latency hides under the epilogue shuffles.
        if (mt < 12) {
#pragma unroll
            for (int i = 0; i < 8; ++i)
                vv1[i] = *(const float2*)(vp1 + i * DVv);
        }

        // Epilogue: C/D layout col = ln15 (e), row = q4*4 + r (m within tile)
        float sR[4];
#pragma unroll
        for (int r = 0; r < 4; ++r) {
            const int m = mt * 16 + q4 * 4 + r;
            const bool valid = m < Mm;
            const float msk = valid ? maskS[m] : 0.f;
            float srow = 0.f;
#pragma unroll
            for (int nt = 0; nt < 4; ++nt) {
                float hv = acc[nt][r] + bbv[nt];
                hv = hv > 0.f ? hv : 0.f;                 // relu
                poolAcc[nt] = fmaf(hv, msk, poolAcc[nt]); // masked pool partial
                srow = fmaf(hv, wspv[nt], srow);          // h[m,:].W_spatial
            }
            srow += __shfl_xor(srow, 1, 64);
            srow += __shfl_xor(srow, 2, 64);
            srow += __shfl_xor(srow, 4, 64);
            srow += __shfl_xor(srow, 8, 64);
            // masked logit: -1e9 (matches reference); invalid rows -> -3e38
            sR[r] = valid ? (msk == 0.f ? -1.0e9f : srow + bsp) : -3.0e38f;
        }

        // broadcast all 16 row-logits of the tile to every lane
        // row i (= q4'*4 + r') lives in lanes q4'=i>>2, register sR[i&3]
        float sv[16];
#pragma unroll
        for (int i = 0; i < 16; ++i)
            sv[i] = __shfl(sR[i & 3], (i >> 2) << 4, 64);

        float tm = sv[0];
#pragma unroll
        for (int i = 1; i < 16; ++i) tm = fmaxf(tm, sv[i]);

        // online-softmax update (per wave). Masked rows at -1e9 are killed
        // at the cross-wave merge by exp(mW - M_global).
        const float newm = fmaxf(m_run, tm);
        const float sc = __expf(m_run - newm);
        m_run = newm;
        l_run *= sc;
        av.x *= sc; av.y *= sc;
#pragma unroll
        for (int i = 0; i < 8; ++i) {
            const float p = __expf(sv[i] - newm);   // 0 for invalid/masked
            l_run += p;
            av.x = fmaf(p, vv0[i].x, av.x);
            av.y = fmaf(p, vv0[i].y, av.y);
        }
#pragma unroll
        for (int i = 0; i < 8; ++i) {
            const float p = __expf(sv[8 + i] - newm);
            l_run += p;
            av.x = fmaf(p, vv1[i].x, av.x);
            av.y = fmaf(p, vv1[i].y, av.y);
        }
    }

    // ---- pool: reduce the 4 row-quads (same e, different m) across q4 ----
#pragma unroll
    for (int nt = 0; nt < 4; ++nt) {
        poolAcc[nt] += __shfl_xor(poolAcc[nt], 16, 64);
        poolAcc[nt] += __shfl_xor(poolAcc[nt], 32, 64);
    }
    if (lane < 16) {
#pragma unroll
        for (int nt = 0; nt < 4; ++nt)
            poolPart[w][nt * 16 + lane] = poolAcc[nt];
    }
    // mask count partial (wave w covers rows [64w, 64w+64))
    {
        const int mi = w * 64 + lane;
        float cm = (mi < Mm) ? maskS[mi] : 0.f;
        cm = waveReduceSum(cm);
        if (lane == 0) cntW[w] = cm;
    }
    // publish per-wave online state
    if (lane == 0) { mW[w] = m_run; lW[w] = l_run; }
    ((float2*)&accW[w][0])[lane] = av;
    __syncthreads();

    // ---- merge 4 waves' online states; finalize pool ----
    float v2v = 0.f;
    if (t < DVv) {
        const float M = fmaxf(fmaxf(mW[0], mW[1]), fmaxf(mW[2], mW[3]));
        float L = 0.f;
#pragma unroll
        for (int i = 0; i < 4; ++i) {
            const float s = __expf(mW[i] - M);
            L   = fmaf(lW[i], s, L);
            v2v = fmaf(accW[i][t], s, v2v);
        }
        v2v /= L;
    }
    if (t < MIDe) {
        const float cnt = cntW[0] + cntW[1] + cntW[2] + cntW[3];
        poolS[t] = (poolPart[0][t] + poolPart[1][t] +
                    poolPart[2][t] + poolPart[3][t]) / cnt;
    }
    __syncthreads();

    // ---- channel gate + epilogue: out = value1 * v2 * sigmoid(pool@Wc+b) ----
    if (t < DVv) {
        float a = b_channel[t];
#pragma unroll 8
        for (int e = 0; e < MIDe; ++e)
            a = fmaf(poolS[e], W_channel[e * DVv + t], a);  // coalesced over t
        const float chv = 1.f / (1.f + __expf(-a));
        out[(size_t)bh * DVv + t] = value1[(size_t)bh * DVv + t] * v2v * chv;
    }
}

extern "C" void kernel_launch(void* const* d_in, const int* in_sizes, int n_in,
                              void* d_out, int out_size, void* d_ws, size_t ws_size,
                              hipStream_t stream) {
    const float* query     = (const float*)d_in[0];
    const float* key       = (const float*)d_in[1];
    const float* att_mask  = (const float*)d_in[2];
    const float* value1    = (const float*)d_in[3];
    const float* value2    = (const float*)d_in[4];
    const float* W_basic   = (const float*)d_in[5];
    const float* b_basic   = (const float*)d_in[6];
    const float* W_spatial = (const float*)d_in[7];
    const float* b_spatial = (const float*)d_in[8];
    const float* W_channel = (const float*)d_in[9];
    const float* b_channel = (const float*)d_in[10];
    float* out = (float*)d_out;

    scatt_fused<<<NBH, 256, 0, stream>>>(query, key, att_mask, value1, value2,
                                         W_basic, b_basic, W_spatial, b_spatial,
                                         W_channel, b_channel, out);
}

// Round 7
// 243.182 us; speedup vs baseline: 1.1180x; 1.0148x over previous
//
#include <hip/hip_runtime.h>
#include <cstddef>

// Problem shapes (fixed by reference)
#define NBH  1024   // B*H
#define Mm   196
#define Dd   128
#define MIDe 64
#define DVv  128
#define WQLD 136    // WqT row length in shorts (128 + 8 pad -> 272 B rows,
                    // rotates banks by 4/row -> frag reads conflict-free)

typedef __attribute__((ext_vector_type(8))) short bf16x8;  // 8 bf16 in 4 VGPRs
typedef __attribute__((ext_vector_type(4))) float f32x4;   // MFMA C/D frag

__device__ __forceinline__ short f2bf(float x) {           // fp32 -> bf16 RNE
    union { float f; unsigned u; } v; v.f = x;
    return (short)((v.u + 0x7FFFu + ((v.u >> 16) & 1u)) >> 16);
}

__device__ __forceinline__ float waveReduceSum(float v) {
#pragma unroll
    for (int off = 32; off > 0; off >>= 1) v += __shfl_xor(v, off, 64);
    return v;
}

// Single-pass fused kernel with 2-TILE INTERLEAVE per wave.
// Round-6 state: spills fixed (WRITE 0.5 MB), VGPR=100, but 90% of issue
// slots idle -- the compiler does NOT pipeline across m-tile iterations, so
// each wave serially does load->wait->MFMA->softmax per tile. Fix: process
// two tiles per round explicitly. Both tiles' key loads (16 dwordx4) and
// value2 loads (32 float2) issue back-to-back (~24 KB in flight/wave);
// tile A's compute overlaps tile B's load returns; one online-softmax
// rescale covers both tiles. Wave w owns pairs {w, w+4}, then {w+8, w+12}.
// Register peak ~190 fits the launch_bounds(256,2) 256-reg budget.
__global__ __launch_bounds__(256, 2)
void scatt_fused(const float* __restrict__ query,
                 const float* __restrict__ key,
                 const float* __restrict__ att_mask,
                 const float* __restrict__ value1,
                 const float* __restrict__ value2,
                 const float* __restrict__ W_basic,
                 const float* __restrict__ b_basic,
                 const float* __restrict__ W_spatial,
                 const float* __restrict__ b_spatial,
                 const float* __restrict__ W_channel,
                 const float* __restrict__ b_channel,
                 float* __restrict__ out)
{
    __shared__ short wqT[MIDe][WQLD];   // bf16 Wq^T[e][d], built once per block
    __shared__ float qS[Dd];
    __shared__ float maskS[Mm];
    __shared__ float poolPart[4][MIDe];
    __shared__ float poolS[MIDe];
    __shared__ float accW[4][DVv];      // per-wave online v2 numerator
    __shared__ float mW[4], lW[4], cntW[4];

    const int t    = threadIdx.x;
    const int lane = t & 63;
    const int w    = t >> 6;            // wave id 0..3
    const int ln15 = lane & 15;
    const int q4   = lane >> 4;         // quad id 0..3
    const int bh   = blockIdx.x;
    const int b    = bh >> 3;

    const float* __restrict__ keyB  = key      + (size_t)bh * Mm * Dd;
    const float* __restrict__ val2B = value2   + (size_t)bh * Mm * DVv;
    const float* __restrict__ qB    = query    + (size_t)bh * Dd;
    const float* __restrict__ maskB = att_mask + (size_t)b  * Mm;

    // ---- Phase 0a: stage q + mask ----
    if (t < 32) ((float4*)qS)[t] = ((const float4*)qB)[t];
    for (int i = t; i < Mm; i += 256) maskS[i] = maskB[i];
    __syncthreads();

    // ---- Phase 0b: build WqT[e][d] = bf16(q[d]*W_basic[d][e]) cooperatively.
    {
        const int e0 = lane;            // e column this thread fills
        const int d0 = w * 32;
#pragma unroll
        for (int c = 0; c < 4; ++c) {   // 4 chunks of 8 d-values
            short pk[8];
#pragma unroll
            for (int j = 0; j < 8; ++j) {
                const int d = d0 + c * 8 + j;
                pk[j] = f2bf(qS[d] * W_basic[d * MIDe + e0]);
            }
            *(bf16x8*)&wqT[e0][d0 + c * 8] = *(bf16x8*)pk;  // ds_write_b128
        }
    }
    __syncthreads();

    float bbv[4], wspv[4];
#pragma unroll
    for (int nt = 0; nt < 4; ++nt) {
        bbv[nt]  = b_basic[nt * 16 + ln15];
        wspv[nt] = W_spatial[nt * 16 + ln15];
    }
    const float bsp = b_spatial[0];

    float poolAcc[4] = {0.f, 0.f, 0.f, 0.f};
    // per-wave online-softmax state; this lane owns v2 cols {2*lane, 2*lane+1}
    float m_run = -3.0e38f;
    float l_run = 0.f;
    float2 av   = make_float2(0.f, 0.f);

    // ---- Main loop: 2 rounds x 2 tiles. mtA = w+8r (<=11, always full);
    // mtB = mtA+4 (valid if <13; ==12 is the 4-row tail, only wave 0 r=1).
#pragma unroll
    for (int r = 0; r < 2; ++r) {
        const int mtA = w + r * 8;
        const int mtB = mtA + 4;
        const bool hasB = (mtB < 13);   // wave-uniform

        // ---- issue key loads A then B (16 dwordx4 in flight)
        const int mrowA = min(mtA * 16 + ln15, Mm - 1);
        const float* apA = keyB + (size_t)mrowA * Dd + q4 * 8;
        float4 a0A[4], a1A[4];
#pragma unroll
        for (int ks = 0; ks < 4; ++ks) {
            a0A[ks] = *(const float4*)(apA + ks * 32);
            a1A[ks] = *(const float4*)(apA + ks * 32 + 4);
        }
        float4 a0B[4], a1B[4];
        {
            const int mrowB = min(mtB * 16 + ln15, Mm - 1);
            const float* apB = keyB + (size_t)mrowB * Dd + q4 * 8;
            if (hasB) {
#pragma unroll
                for (int ks = 0; ks < 4; ++ks) {
                    a0B[ks] = *(const float4*)(apB + ks * 32);
                    a1B[ks] = *(const float4*)(apB + ks * 32 + 4);
                }
            }
        }

        // ---- issue value2 loads A then B (32 float2; imm-offset folded)
        const float* vpA0 = val2B + (size_t)(mtA * 16) * DVv + 2 * lane;
        const float* vpA1 = vpA0 + 8 * DVv;
        float2 vvA[16];
#pragma unroll
        for (int i = 0; i < 8; ++i) vvA[i]     = *(const float2*)(vpA0 + i * DVv);
#pragma unroll
        for (int i = 0; i < 8; ++i) vvA[8 + i] = *(const float2*)(vpA1 + i * DVv);

        float2 vvB[16];
        {
            const float* vpB0 = val2B + (size_t)(mtB * 16) * DVv + 2 * lane;
            const float* vpB1 = vpB0 + 8 * DVv;
            if (hasB) {
                if (mtB < 12) {
#pragma unroll
                    for (int i = 0; i < 8; ++i) vvB[i]     = *(const float2*)(vpB0 + i * DVv);
#pragma unroll
                    for (int i = 0; i < 8; ++i) vvB[8 + i] = *(const float2*)(vpB1 + i * DVv);
                } else {            // tail tile 12: rows 192..195 only
#pragma unroll
                    for (int i = 0; i < 4; ++i) vvB[i] = *(const float2*)(vpB0 + i * DVv);
#pragma unroll
                    for (int i = 4; i < 8; ++i) vvB[i] = make_float2(0.f, 0.f);
#pragma unroll
                    for (int i = 0; i < 8; ++i) vvB[8 + i] = make_float2(0.f, 0.f);
                }
            }
        }

        // ---- tile A: convert (waits only key-A loads) + MFMA
        bf16x8 afA[4];
#pragma unroll
        for (int ks = 0; ks < 4; ++ks)
            afA[ks] = bf16x8{ f2bf(a0A[ks].x), f2bf(a0A[ks].y),
                              f2bf(a0A[ks].z), f2bf(a0A[ks].w),
                              f2bf(a1A[ks].x), f2bf(a1A[ks].y),
                              f2bf(a1A[ks].z), f2bf(a1A[ks].w) };
        f32x4 accA[4] = {f32x4{0,0,0,0}, f32x4{0,0,0,0},
                         f32x4{0,0,0,0}, f32x4{0,0,0,0}};
#pragma unroll
        for (int ks = 0; ks < 4; ++ks) {
#pragma unroll
            for (int nt = 0; nt < 4; ++nt) {
                const bf16x8 bk =
                    *(const bf16x8*)&wqT[nt * 16 + ln15][ks * 32 + q4 * 8];
                accA[nt] = __builtin_amdgcn_mfma_f32_16x16x32_bf16(
                               afA[ks], bk, accA[nt], 0, 0, 0);
            }
        }

        // ---- tile B: convert + MFMA (overlaps A's epilogue scheduling)
        bf16x8 afB[4];
        f32x4 accB[4] = {f32x4{0,0,0,0}, f32x4{0,0,0,0},
                         f32x4{0,0,0,0}, f32x4{0,0,0,0}};
        if (hasB) {
#pragma unroll
            for (int ks = 0; ks < 4; ++ks)
                afB[ks] = bf16x8{ f2bf(a0B[ks].x), f2bf(a0B[ks].y),
                                  f2bf(a0B[ks].z), f2bf(a0B[ks].w),
                                  f2bf(a1B[ks].x), f2bf(a1B[ks].y),
                                  f2bf(a1B[ks].z), f2bf(a1B[ks].w) };
#pragma unroll
            for (int ks = 0; ks < 4; ++ks) {
#pragma unroll
                for (int nt = 0; nt < 4; ++nt) {
                    const bf16x8 bk =
                        *(const bf16x8*)&wqT[nt * 16 + ln15][ks * 32 + q4 * 8];
                    accB[nt] = __builtin_amdgcn_mfma_f32_16x16x32_bf16(
                                   afB[ks], bk, accB[nt], 0, 0, 0);
                }
            }
        }

        // ---- epilogues: logits per row; C/D col = ln15 (e), row = q4*4+rr
        float sRA[4], sRB[4];
#pragma unroll
        for (int rr = 0; rr < 4; ++rr) {
            const int m = mtA * 16 + q4 * 4 + rr;
            const float msk = maskS[m];          // mtA<=11 -> m<192 always valid
            float srow = 0.f;
#pragma unroll
            for (int nt = 0; nt < 4; ++nt) {
                float hv = accA[nt][rr] + bbv[nt];
                hv = hv > 0.f ? hv : 0.f;                 // relu
                poolAcc[nt] = fmaf(hv, msk, poolAcc[nt]); // masked pool partial
                srow = fmaf(hv, wspv[nt], srow);          // h[m,:].W_spatial
            }
            srow += __shfl_xor(srow, 1, 64);
            srow += __shfl_xor(srow, 2, 64);
            srow += __shfl_xor(srow, 4, 64);
            srow += __shfl_xor(srow, 8, 64);
            sRA[rr] = (msk == 0.f) ? -1.0e9f : srow + bsp;
        }
        float tmA = fmaxf(fmaxf(sRA[0], sRA[1]), fmaxf(sRA[2], sRA[3]));
        tmA = fmaxf(tmA, __shfl_xor(tmA, 16, 64));
        tmA = fmaxf(tmA, __shfl_xor(tmA, 32, 64));

        float tmB = -3.0e38f;
        if (hasB) {
#pragma unroll
            for (int rr = 0; rr < 4; ++rr) {
                const int m = mtB * 16 + q4 * 4 + rr;
                const bool valid = m < Mm;
                const float msk = valid ? maskS[m] : 0.f;
                float srow = 0.f;
#pragma unroll
                for (int nt = 0; nt < 4; ++nt) {
                    float hv = accB[nt][rr] + bbv[nt];
                    hv = hv > 0.f ? hv : 0.f;
                    poolAcc[nt] = fmaf(hv, msk, poolAcc[nt]);
                    srow = fmaf(hv, wspv[nt], srow);
                }
                srow += __shfl_xor(srow, 1, 64);
                srow += __shfl_xor(srow, 2, 64);
                srow += __shfl_xor(srow, 4, 64);
                srow += __shfl_xor(srow, 8, 64);
                sRB[rr] = valid ? (msk == 0.f ? -1.0e9f : srow + bsp) : -3.0e38f;
            }
            tmB = fmaxf(fmaxf(sRB[0], sRB[1]), fmaxf(sRB[2], sRB[3]));
            tmB = fmaxf(tmB, __shfl_xor(tmB, 16, 64));
            tmB = fmaxf(tmB, __shfl_xor(tmB, 32, 64));
        }

        // ---- one online-softmax update for both tiles ----
        const float tm   = hasB ? fmaxf(tmA, tmB) : tmA;
        const float newm = fmaxf(m_run, tm);
        const float sc   = __expf(m_run - newm);
        m_run = newm;

        float lsum = 0.f;
        float ax0 = 0.f, ax1 = 0.f, ay0 = 0.f, ay1 = 0.f;
        {
            float p4[4];
#pragma unroll
            for (int rr = 0; rr < 4; ++rr) p4[rr] = __expf(sRA[rr] - newm);
            float pv[16];
#pragma unroll
            for (int i = 0; i < 16; ++i)
                pv[i] = __shfl(p4[i & 3], (i >> 2) << 4, 64);
#pragma unroll
            for (int i = 0; i < 16; i += 2) {
                lsum += pv[i] + pv[i + 1];
                ax0 = fmaf(pv[i],     vvA[i].x,     ax0);
                ay0 = fmaf(pv[i],     vvA[i].y,     ay0);
                ax1 = fmaf(pv[i + 1], vvA[i + 1].x, ax1);
                ay1 = fmaf(pv[i + 1], vvA[i + 1].y, ay1);
            }
        }
        if (hasB) {
            float p4[4];
#pragma unroll
            for (int rr = 0; rr < 4; ++rr) p4[rr] = __expf(sRB[rr] - newm);
            float pv[16];
#pragma unroll
            for (int i = 0; i < 16; ++i)
                pv[i] = __shfl(p4[i & 3], (i >> 2) << 4, 64);
#pragma unroll
            for (int i = 0; i < 16; i += 2) {
                lsum += pv[i] + pv[i + 1];
                ax0 = fmaf(pv[i],     vvB[i].x,     ax0);
                ay0 = fmaf(pv[i],     vvB[i].y,     ay0);
                ax1 = fmaf(pv[i + 1], vvB[i + 1].x, ax1);
                ay1 = fmaf(pv[i + 1], vvB[i + 1].y, ay1);
            }
        }
        l_run = fmaf(l_run, sc, lsum);
        av.x  = fmaf(av.x,  sc, ax0 + ax1);
        av.y  = fmaf(av.y,  sc, ay0 + ay1);
    }

    // ---- pool: reduce the 4 row-quads (same e, different m) across q4 ----
#pragma unroll
    for (int nt = 0; nt < 4; ++nt) {
        poolAcc[nt] += __shfl_xor(poolAcc[nt], 16, 64);
        poolAcc[nt] += __shfl_xor(poolAcc[nt], 32, 64);
    }
    if (lane < 16) {
#pragma unroll
        for (int nt = 0; nt < 4; ++nt)
            poolPart[w][nt * 16 + lane] = poolAcc[nt];
    }
    // mask count partial (wave w covers rows [64w, 64w+64))
    {
        const int mi = w * 64 + lane;
        float cm = (mi < Mm) ? maskS[mi] : 0.f;
        cm = waveReduceSum(cm);
        if (lane == 0) cntW[w] = cm;
    }
    // publish per-wave online state
    if (lane == 0) { mW[w] = m_run; lW[w] = l_run; }
    ((float2*)&accW[w][0])[lane] = av;
    __syncthreads();

    // ---- merge 4 waves' online states; finalize pool ----
    float v2v = 0.f;
    if (t < DVv) {
        const float M = fmaxf(fmaxf(mW[0], mW[1]), fmaxf(mW[2], mW[3]));
        float L = 0.f;
#pragma unroll
        for (int i = 0; i < 4; ++i) {
            const float s = __expf(mW[i] - M);
            L   = fmaf(lW[i], s, L);
            v2v = fmaf(accW[i][t], s, v2v);
        }
        v2v /= L;
    }
    if (t < MIDe) {
        const float cnt = cntW[0] + cntW[1] + cntW[2] + cntW[3];
        poolS[t] = (poolPart[0][t] + poolPart[1][t] +
                    poolPart[2][t] + poolPart[3][t]) / cnt;
    }
    __syncthreads();

    // ---- channel gate + epilogue: out = value1 * v2 * sigmoid(pool@Wc+b) ----
    if (t < DVv) {
        float a = b_channel[t];
#pragma unroll 8
        for (int e = 0; e < MIDe; ++e)
            a = fmaf(poolS[e], W_channel[e * DVv + t], a);  // coalesced over t
        const float chv = 1.f / (1.f + __expf(-a));
        out[(size_t)bh * DVv + t] = value1[(size_t)bh * DVv + t] * v2v * chv;
    }
}

extern "C" void kernel_launch(void* const* d_in, const int* in_sizes, int n_in,
                              void* d_out, int out_size, void* d_ws, size_t ws_size,
                              hipStream_t stream) {
    const float* query     = (const float*)d_in[0];
    const float* key       = (const float*)d_in[1];
    const float* att_mask  = (const float*)d_in[2];
    const float* value1    = (const float*)d_in[3];
    const float* value2    = (const float*)d_in[4];
    const float* W_basic   = (const float*)d_in[5];
    const float* b_basic   = (const float*)d_in[6];
    const float* W_spatial = (const float*)d_in[7];
    const float* b_spatial = (const float*)d_in[8];
    const float* W_channel = (const float*)d_in[9];
    const float* b_channel = (const float*)d_in[10];
    float* out = (float*)d_out;

    scatt_fused<<<NBH, 256, 0, stream>>>(query, key, att_mask, value1, value2,
                                         W_basic, b_basic, W_spatial, b_spatial,
                                         W_channel, b_channel, out);
}